// Round 6
// baseline (258.920 us; speedup 1.0000x reference)
//
#include <hip/hip_runtime.h>
#include <hip/hip_bf16.h>

// LSTMAggregator — ROUND 11b: resubmit of R11 (infra failure, not a kernel
// verdict: "container failed twice" with no pytest/absmax). Source audited
// for faults/hangs: exact 3125-block grid (no tail), guarded out-writes,
// bijective both-sides LDS swizzle, in-bounds ws/tab access. Unchanged.
//
// NPB 32 -> 16 (finer grid + register diet). R10: 122 us, MfmaUtil 17 +
// VALUBusy 48 = 65% issue, 35% stall. Causes: (a) live regs ~156 -> 2
// waves/SIMD; (b) 782 blocks / 512 slots = 1.53 generations (gen2 at 53%
// fill ~= 20% of wall). NPB=16: acc 32->16, G 16->8, cst 8->4 => live ~136
// < 168 => 3 waves/SIMD legal; grid 3125 => tail ~8%; 3 phase-diverse
// barrier groups/CU hide each other's stalls. launch_bounds stays (256,2) —
// a min, not a cap; no forced-target spill risk (R9 lesson).
//   A-frag: A[m=lane&15][k=(lane>>4)*8+j]   B-frag: B[k][n=lane&15]=W[row][k]
//   C/D: row(node)=(lane>>4)*4+reg, col(unit)=lane&15

#define NN 50000
#define KK 10
#define FF 128
#define HH 64

// ws layout (bf16 elements)
#define WS_WIH_F 0
#define WS_WHH_F 32768
#define WS_WIH_B 49152

#define NPB 16   // nodes per block
#define HS 72    // h_lds row stride (shorts): addr/16 walk coprime -> 8 lanes/slot

typedef __bf16 bf16x8 __attribute__((ext_vector_type(8)));
typedef float f32x4 __attribute__((ext_vector_type(4)));
typedef float f32x2 __attribute__((ext_vector_type(2)));

__device__ __forceinline__ float fast_sig(float x) {
    float e = exp2f(x * -1.44269504f);
    return __builtin_amdgcn_rcpf(1.0f + e);
}
__device__ __forceinline__ float fast_tanh(float x) {
    float e = exp2f(x * 2.88539008f);
    return 1.0f - 2.0f * __builtin_amdgcn_rcpf(e + 1.0f);
}
__device__ __forceinline__ f32x2 sig2(f32x2 x) {
    f32x2 t = x * -1.44269504f;                       // v_pk_mul
    f32x2 e = {exp2f(t.x), exp2f(t.y)};
    f32x2 d = e + 1.0f;                               // v_pk_add
    return (f32x2){__builtin_amdgcn_rcpf(d.x), __builtin_amdgcn_rcpf(d.y)};
}
__device__ __forceinline__ f32x2 tanh2(f32x2 x) {
    f32x2 t = x * 2.88539008f;
    f32x2 e = {exp2f(t.x), exp2f(t.y)};
    f32x2 d = e + 1.0f;
    f32x2 r = {__builtin_amdgcn_rcpf(d.x), __builtin_amdgcn_rcpf(d.y)};
    return 1.0f - 2.0f * r;                           // v_pk_fma
}

__global__ void cvt_weights_kernel(const float* __restrict__ Wih_f,
                                   const float* __restrict__ Whh_f,
                                   const float* __restrict__ Wih_b,
                                   __bf16* __restrict__ ws) {
    int i = blockIdx.x * 256 + threadIdx.x;          // 32768 threads
    ws[WS_WIH_F + i] = (__bf16)Wih_f[i];
    if (i < 16384) ws[WS_WHH_F + i] = (__bf16)Whh_f[i];
    ws[WS_WIH_B + i] = (__bf16)Wih_b[i];
}

__global__ __launch_bounds__(256, 2) void lstm_agg_kernel(
    const int* __restrict__ nidx,
    const float* __restrict__ tab,
    const float* __restrict__ bih_f,
    const float* __restrict__ bhh_f,
    const float* __restrict__ bih_b,
    const float* __restrict__ bhh_b,
    const __bf16* __restrict__ ws,
    float* __restrict__ out)
{
    __shared__ __bf16 x_lds[2][NPB * FF];   // 2 x 4 KB bf16, 16B-slot swizzled
    __shared__ __bf16 h_lds[2][NPB * HS];   // 2 x 2.25 KB, double-buffered
    __shared__ int    gq[NPB][KK];          // 640 B          (total ~13.2 KB)

    const int tid  = threadIdx.x;
    const int w    = tid >> 6;        // wave id: owns units w*16..w*16+15
    const int lane = tid & 63;
    const int q    = lane >> 4;
    const int c    = lane & 15;
    const int koff = q * 8;
    const int node_base = blockIdx.x * NPB;
    const int sw = (c & 7) << 4;      // frag-read de-swizzle

    // x staging: thread -> (row = tid>>4, part = tid&15): 32 B f32 each
    const int srow  = tid >> 4;
    const int spart = tid & 15;
    const int swW   = (srow & 7) << 4;

    // stage gather indices for the block's 16 nodes
    if (tid < NPB * KK) {
        int r = tid / KK, k = tid - r * KK;
        int node = min(node_base + r, NN - 1);
        gq[r][k] = nidx[node * KK + k];
    }

    f32x4 G[2];   // in-flight gather registers (T14 issue-early / write-late)
    auto stage_load = [&](int kidx) {
        const float* src = tab + (size_t)gq[srow][kidx] * FF + spart * 8;
        G[0] = *(const f32x4*)(src);
        G[1] = *(const f32x4*)(src + 4);
    };
    auto stage_write = [&](int b) {
        bf16x8 v;
#pragma unroll
        for (int e = 0; e < 4; ++e) {
            v[e]     = (__bf16)G[0][e];
            v[4 + e] = (__bf16)G[1][e];
        }
        char* row = (char*)(x_lds[b] + srow * FF);
        *(bf16x8*)(row + ((spart * 16) ^ swW)) = v;
    };

    __syncthreads();      // gq visible
    stage_load(0);

    // weight B-fragments, register-resident for the whole kernel
    bf16x8 bWih[4][4], bWhh[4][2];
#pragma unroll
    for (int g = 0; g < 4; ++g) {
        int row = (g * 4 + w) * 16 + c;        // gate row g*64 + w*16 + c
#pragma unroll
        for (int kk = 0; kk < 4; ++kk)
            bWih[g][kk] = *(const bf16x8*)(ws + WS_WIH_F + row * FF + kk * 32 + koff);
#pragma unroll
        for (int kk = 0; kk < 2; ++kk)
            bWhh[g][kk] = *(const bf16x8*)(ws + WS_WHH_F + row * HH + kk * 32 + koff);
    }
    float bias[4];
#pragma unroll
    for (int g = 0; g < 4; ++g) {
        int u = g * 64 + w * 16 + c;
        bias[g] = bih_f[u] + bhh_f[u];
    }

    stage_write(0);       // compiler inserts the vmcnt wait here
    __syncthreads();      // x_0 visible

    f32x4 acc[4];      // [gate]
    float cst[4];      // cell state
#pragma unroll
    for (int e = 0; e < 4; ++e) cst[e] = 0.0f;

#pragma unroll 2
    for (int k = 0; k < KK; ++k) {
        const int cur = k & 1;
        // issue next step's gather FIRST: latency hides under this step's
        // MFMAs + activations; the write (and its vmcnt wait) comes last.
        if (k + 1 < KK) stage_load(k + 1);

#pragma unroll
        for (int g = 0; g < 4; ++g)
            acc[g] = (f32x4){bias[g], bias[g], bias[g], bias[g]};

        __builtin_amdgcn_s_setprio(1);
        {
            const char* rp = (const char*)x_lds[cur] + c * 256;
            bf16x8 xa[4];
#pragma unroll
            for (int kk = 0; kk < 4; ++kk)
                xa[kk] = *(const bf16x8*)(rp + ((kk * 64 + q * 16) ^ sw));
#pragma unroll
            for (int g = 0; g < 4; ++g)
#pragma unroll
                for (int kk = 0; kk < 4; ++kk)
                    acc[g] = __builtin_amdgcn_mfma_f32_16x16x32_bf16(
                        xa[kk], bWih[g][kk], acc[g], 0, 0, 0);
        }
        if (k > 0) {
            const __bf16* hb = h_lds[(k - 1) & 1];
            bf16x8 ha[2];
#pragma unroll
            for (int kk = 0; kk < 2; ++kk)
                ha[kk] = *(const bf16x8*)(hb + c * HS + kk * 32 + koff);
#pragma unroll
            for (int g = 0; g < 4; ++g)
#pragma unroll
                for (int kk = 0; kk < 2; ++kk)
                    acc[g] = __builtin_amdgcn_mfma_f32_16x16x32_bf16(
                        ha[kk], bWhh[g][kk], acc[g], 0, 0, 0);
        }
        __builtin_amdgcn_s_setprio(0);

        const bool last = (k == KK - 1);
        __bf16* hw = h_lds[k & 1];
#pragma unroll
        for (int p = 0; p < 2; ++p) {     // reg pairs -> packed f32 math
            f32x2 ai = {acc[0][2 * p], acc[0][2 * p + 1]};
            f32x2 af = {acc[1][2 * p], acc[1][2 * p + 1]};
            f32x2 ag = {acc[2][2 * p], acc[2][2 * p + 1]};
            f32x2 ao = {acc[3][2 * p], acc[3][2 * p + 1]};
            f32x2 gi = sig2(ai);
            f32x2 gf = sig2(af);
            f32x2 gg = tanh2(ag);
            f32x2 go = sig2(ao);
            f32x2 cc = {cst[2 * p], cst[2 * p + 1]};
            f32x2 cn = gf * cc + gi * gg;        // v_pk_mul + v_pk_fma
            cst[2 * p]     = cn.x;
            cst[2 * p + 1] = cn.y;
            f32x2 h = go * tanh2(cn);
            hw[(q * 4 + 2 * p)     * HS + w * 16 + c] = (__bf16)h.x;
            hw[(q * 4 + 2 * p + 1) * HS + w * 16 + c] = (__bf16)h.y;
            if (last) {
                int node = node_base + q * 4 + 2 * p;
                if (node < NN)     out[(size_t)node * 128 + w * 16 + c] = h.x;
                if (node + 1 < NN) out[(size_t)(node + 1) * 128 + w * 16 + c] = h.y;
            }
        }

        // write-late: vmcnt drain for G + bf16 LDS write of x_{k+1}
        if (k + 1 < KK) stage_write(cur ^ 1);
        __syncthreads();
    }

    // ---- backward direction: one step on x[:,9] (in x_lds[1]), zero state
    {
        const int gb[3] = {0, 2, 3};    // gates i, g, o (f irrelevant: c0 = 0)
        bf16x8 bW[3][4];
        float  bb[3];
#pragma unroll
        for (int j = 0; j < 3; ++j) {
            int row = (gb[j] * 4 + w) * 16 + c;
#pragma unroll
            for (int kk = 0; kk < 4; ++kk)
                bW[j][kk] = *(const bf16x8*)(ws + WS_WIH_B + row * FF + kk * 32 + koff);
            int u = gb[j] * 64 + w * 16 + c;
            bb[j] = bih_b[u] + bhh_b[u];
        }
        const char* rp = (const char*)x_lds[(KK - 1) & 1] + c * 256;
        f32x4 a0 = (f32x4){bb[0], bb[0], bb[0], bb[0]};
        f32x4 a1 = (f32x4){bb[1], bb[1], bb[1], bb[1]};
        f32x4 a2 = (f32x4){bb[2], bb[2], bb[2], bb[2]};
        bf16x8 xa[4];
#pragma unroll
        for (int kk = 0; kk < 4; ++kk)
            xa[kk] = *(const bf16x8*)(rp + ((kk * 64 + q * 16) ^ sw));
#pragma unroll
        for (int kk = 0; kk < 4; ++kk) {
            a0 = __builtin_amdgcn_mfma_f32_16x16x32_bf16(xa[kk], bW[0][kk], a0, 0, 0, 0);
            a1 = __builtin_amdgcn_mfma_f32_16x16x32_bf16(xa[kk], bW[1][kk], a1, 0, 0, 0);
            a2 = __builtin_amdgcn_mfma_f32_16x16x32_bf16(xa[kk], bW[2][kk], a2, 0, 0, 0);
        }
#pragma unroll
        for (int reg = 0; reg < 4; ++reg) {
            float gi = fast_sig(a0[reg]);
            float gg = fast_tanh(a1[reg]);
            float go = fast_sig(a2[reg]);
            float hb2 = go * fast_tanh(gi * gg);
            int node = node_base + q * 4 + reg;
            if (node < NN) out[(size_t)node * 128 + 64 + w * 16 + c] = hb2;
        }
    }
}

extern "C" void kernel_launch(void* const* d_in, const int* in_sizes, int n_in,
                              void* d_out, int out_size, void* d_ws, size_t ws_size,
                              hipStream_t stream) {
    const int*   nidx  = (const int*)d_in[0];
    const float* tab   = (const float*)d_in[1];
    const float* Wih_f = (const float*)d_in[2];
    const float* Whh_f = (const float*)d_in[3];
    const float* bih_f = (const float*)d_in[4];
    const float* bhh_f = (const float*)d_in[5];
    const float* Wih_b = (const float*)d_in[6];
    // d_in[7] = Whh_b: mathematically unused (h0 = 0 for the backward stream)
    const float* bih_b = (const float*)d_in[8];
    const float* bhh_b = (const float*)d_in[9];
    __bf16* ws  = (__bf16*)d_ws;      // 160 KB scratch
    float*  out = (float*)d_out;      // output is f32

    hipLaunchKernelGGL(cvt_weights_kernel, dim3(32768 / 256), dim3(256), 0, stream,
                       Wih_f, Whh_f, Wih_b, ws);

    const int blocks = (NN + NPB - 1) / NPB;   // 16 nodes per 256-thread block
    hipLaunchKernelGGL(lstm_agg_kernel, dim3(blocks), dim3(256), 0, stream,
                       nidx, tab, bih_f, bhh_f, bih_b, bhh_b, ws, out);
}

// Round 7
// 234.131 us; speedup vs baseline: 1.1059x; 1.1059x over previous
//
#include <hip/hip_runtime.h>
#include <hip/hip_bf16.h>

// LSTMAggregator — ROUND 12: persistent blocks + raw v_exp + pinned T14.
// R11 A/B proved: finer grid REGRESSES (134 vs 122 us) — per-block fixed
// costs (36 weight-frag loads, gq/x0 staging, epilogue) dominate, and
// occupancy is pinned ~1.5-2 blocks/CU regardless of VGPR (96 vs 124 -> same
// 20%). R12 returns to NPB=32 and amortizes: grid=512 persistent blocks
// (exactly 2/CU), tile-strided loop, weights register-resident across ~3
// tiles; no second-generation tail. Safety: gq dead after k=8's barrier,
// epilogue reads only x_lds[1], next tile's writes sit behind the gq
// barrier. Plus: __builtin_amdgcn_exp2f (bare v_exp_f32, no OCML guard
// path) and sched_barrier(0) after stage_load so the gather loads cannot
// be sunk toward their use (T14 issue-early made structural).
//   A-frag: A[m=lane&15][k=(lane>>4)*8+j]   B-frag: B[k][n=lane&15]=W[row][k]
//   C/D: row(node-in-group)=(lane>>4)*4+reg, col=lane&15

#define NN 50000
#define KK 10
#define FF 128
#define HH 64

// ws layout (bf16 elements)
#define WS_WIH_F 0
#define WS_WHH_F 32768
#define WS_WIH_B 49152

#define NPB 32        // nodes per tile
#define NT 1563       // ceil(NN / NPB)
#define GRID 512      // persistent blocks: 2 per CU
#define HS 72         // h_lds row stride (shorts)

typedef __bf16 bf16x8 __attribute__((ext_vector_type(8)));
typedef float f32x4 __attribute__((ext_vector_type(4)));
typedef float f32x2 __attribute__((ext_vector_type(2)));

#if __has_builtin(__builtin_amdgcn_exp2f)
#define EXP2(x) __builtin_amdgcn_exp2f(x)
#else
#define EXP2(x) exp2f(x)
#endif

__device__ __forceinline__ float fast_sig(float x) {
    float e = EXP2(x * -1.44269504f);
    return __builtin_amdgcn_rcpf(1.0f + e);
}
__device__ __forceinline__ float fast_tanh(float x) {
    float e = EXP2(x * 2.88539008f);
    return 1.0f - 2.0f * __builtin_amdgcn_rcpf(e + 1.0f);
}
__device__ __forceinline__ f32x2 sig2(f32x2 x) {
    f32x2 t = x * -1.44269504f;                       // v_pk_mul
    f32x2 e = {EXP2(t.x), EXP2(t.y)};
    f32x2 d = e + 1.0f;                               // v_pk_add
    return (f32x2){__builtin_amdgcn_rcpf(d.x), __builtin_amdgcn_rcpf(d.y)};
}
__device__ __forceinline__ f32x2 tanh2(f32x2 x) {
    f32x2 t = x * 2.88539008f;
    f32x2 e = {EXP2(t.x), EXP2(t.y)};
    f32x2 d = e + 1.0f;
    f32x2 r = {__builtin_amdgcn_rcpf(d.x), __builtin_amdgcn_rcpf(d.y)};
    return 1.0f - 2.0f * r;                           // v_pk_fma
}

__global__ void cvt_weights_kernel(const float* __restrict__ Wih_f,
                                   const float* __restrict__ Whh_f,
                                   const float* __restrict__ Wih_b,
                                   __bf16* __restrict__ ws) {
    int i = blockIdx.x * 256 + threadIdx.x;          // 32768 threads
    ws[WS_WIH_F + i] = (__bf16)Wih_f[i];
    if (i < 16384) ws[WS_WHH_F + i] = (__bf16)Whh_f[i];
    ws[WS_WIH_B + i] = (__bf16)Wih_b[i];
}

__global__ __launch_bounds__(256, 2) void lstm_agg_kernel(
    const int* __restrict__ nidx,
    const float* __restrict__ tab,
    const float* __restrict__ bih_f,
    const float* __restrict__ bhh_f,
    const float* __restrict__ bih_b,
    const float* __restrict__ bhh_b,
    const __bf16* __restrict__ ws,
    float* __restrict__ out)
{
    __shared__ __bf16 x_lds[2][NPB * FF];   // 2 x 8 KB bf16, 16B-slot swizzled
    __shared__ __bf16 h_lds[2][NPB * HS];   // 2 x 4.5 KB, double-buffered
    __shared__ int    gq[NPB][KK];          // 1.25 KB        (total 26.9 KB)

    const int tid  = threadIdx.x;
    const int w    = tid >> 6;        // wave id: owns units w*16..w*16+15
    const int lane = tid & 63;
    const int q    = lane >> 4;
    const int c    = lane & 15;
    const int koff = q * 8;
    const int sw = (c & 7) << 4;      // frag-read de-swizzle

    // x staging: thread -> (row = tid>>3, part = tid&7): 64 B f32 each
    const int srow  = tid >> 3;
    const int spart = tid & 7;
    const int swW   = (srow & 7) << 4;

    f32x4 G[4];   // in-flight gather registers (T14 issue-early / write-late)
    auto stage_load = [&](int kidx) {
        const float* src = tab + (size_t)gq[srow][kidx] * FF + spart * 16;
#pragma unroll
        for (int j = 0; j < 4; ++j) G[j] = *(const f32x4*)(src + j * 4);
    };
    auto stage_write = [&](int b) {
        bf16x8 v0, v1;
#pragma unroll
        for (int e = 0; e < 4; ++e) {
            v0[e]     = (__bf16)G[0][e];
            v0[4 + e] = (__bf16)G[1][e];
            v1[e]     = (__bf16)G[2][e];
            v1[4 + e] = (__bf16)G[3][e];
        }
        char* row = (char*)(x_lds[b] + srow * FF);
        *(bf16x8*)(row + ((spart * 32)      ^ swW)) = v0;
        *(bf16x8*)(row + ((spart * 32 + 16) ^ swW)) = v1;
    };

    // weight B-fragments + biases: register-resident across ALL tiles
    bf16x8 bWih[4][4], bWhh[4][2];
#pragma unroll
    for (int g = 0; g < 4; ++g) {
        int row = (g * 4 + w) * 16 + c;        // gate row g*64 + w*16 + c
#pragma unroll
        for (int kk = 0; kk < 4; ++kk)
            bWih[g][kk] = *(const bf16x8*)(ws + WS_WIH_F + row * FF + kk * 32 + koff);
#pragma unroll
        for (int kk = 0; kk < 2; ++kk)
            bWhh[g][kk] = *(const bf16x8*)(ws + WS_WHH_F + row * HH + kk * 32 + koff);
    }
    float bias[4];
#pragma unroll
    for (int g = 0; g < 4; ++g) {
        int u = g * 64 + w * 16 + c;
        bias[g] = bih_f[u] + bhh_f[u];
    }

    for (int tile = blockIdx.x; tile < NT; tile += GRID) {
        const int node_base = tile * NPB;

        __syncthreads();   // previous tile fully retired before gq overwrite
        for (int i = tid; i < NPB * KK; i += 256) {
            int r = i / KK, k = i - r * KK;
            int node = min(node_base + r, NN - 1);
            gq[r][k] = nidx[node * KK + k];
        }
        __syncthreads();   // gq visible

        stage_load(0);
        __builtin_amdgcn_sched_barrier(0);
        stage_write(0);    // vmcnt wait inserted here
        __syncthreads();   // x_0 visible

        f32x4 acc[4][2];      // [gate][node-group]
        float cst[2][4];      // cell state
#pragma unroll
        for (int r = 0; r < 2; ++r)
#pragma unroll
            for (int e = 0; e < 4; ++e) cst[r][e] = 0.0f;

#pragma unroll 2
        for (int k = 0; k < KK; ++k) {
            const int cur = k & 1;
            // issue next step's gather FIRST; fence so it cannot be sunk.
            if (k + 1 < KK) {
                stage_load(k + 1);
                __builtin_amdgcn_sched_barrier(0);
            }

#pragma unroll
            for (int g = 0; g < 4; ++g)
#pragma unroll
                for (int r = 0; r < 2; ++r)
                    acc[g][r] = (f32x4){bias[g], bias[g], bias[g], bias[g]};

            __builtin_amdgcn_s_setprio(1);
            const char* xb = (const char*)x_lds[cur];
#pragma unroll
            for (int r = 0; r < 2; ++r) {
                const char* rp = xb + (r * 16 + c) * 256;
                bf16x8 xa[4];
#pragma unroll
                for (int kk = 0; kk < 4; ++kk)
                    xa[kk] = *(const bf16x8*)(rp + ((kk * 64 + q * 16) ^ sw));
#pragma unroll
                for (int g = 0; g < 4; ++g)
#pragma unroll
                    for (int kk = 0; kk < 4; ++kk)
                        acc[g][r] = __builtin_amdgcn_mfma_f32_16x16x32_bf16(
                            xa[kk], bWih[g][kk], acc[g][r], 0, 0, 0);
            }
            if (k > 0) {
                const __bf16* hb = h_lds[(k - 1) & 1];
#pragma unroll
                for (int r = 0; r < 2; ++r) {
                    bf16x8 ha[2];
#pragma unroll
                    for (int kk = 0; kk < 2; ++kk)
                        ha[kk] = *(const bf16x8*)(hb + (r * 16 + c) * HS + kk * 32 + koff);
#pragma unroll
                    for (int g = 0; g < 4; ++g)
#pragma unroll
                        for (int kk = 0; kk < 2; ++kk)
                            acc[g][r] = __builtin_amdgcn_mfma_f32_16x16x32_bf16(
                                ha[kk], bWhh[g][kk], acc[g][r], 0, 0, 0);
                }
            }
            __builtin_amdgcn_s_setprio(0);

            const bool last = (k == KK - 1);
            __bf16* hw = h_lds[k & 1];
#pragma unroll
            for (int r = 0; r < 2; ++r)
#pragma unroll
                for (int p = 0; p < 2; ++p) {     // reg pairs -> packed f32 math
                    f32x2 ai = {acc[0][r][2 * p], acc[0][r][2 * p + 1]};
                    f32x2 af = {acc[1][r][2 * p], acc[1][r][2 * p + 1]};
                    f32x2 ag = {acc[2][r][2 * p], acc[2][r][2 * p + 1]};
                    f32x2 ao = {acc[3][r][2 * p], acc[3][r][2 * p + 1]};
                    f32x2 gi = sig2(ai);
                    f32x2 gf = sig2(af);
                    f32x2 gg = tanh2(ag);
                    f32x2 go = sig2(ao);
                    f32x2 cc = {cst[r][2 * p], cst[r][2 * p + 1]};
                    f32x2 cn = gf * cc + gi * gg;        // v_pk_mul + v_pk_fma
                    cst[r][2 * p]     = cn.x;
                    cst[r][2 * p + 1] = cn.y;
                    f32x2 h = go * tanh2(cn);
                    hw[(r * 16 + q * 4 + 2 * p)     * HS + w * 16 + c] = (__bf16)h.x;
                    hw[(r * 16 + q * 4 + 2 * p + 1) * HS + w * 16 + c] = (__bf16)h.y;
                    if (last) {
                        int node = node_base + r * 16 + q * 4 + 2 * p;
                        if (node < NN)     out[(size_t)node * 128 + w * 16 + c] = h.x;
                        if (node + 1 < NN) out[(size_t)(node + 1) * 128 + w * 16 + c] = h.y;
                    }
                }

            // write-late: vmcnt drain for G + bf16 LDS write of x_{k+1}
            if (k + 1 < KK) stage_write(cur ^ 1);
            __syncthreads();
        }

        // ---- backward direction: one step on x[:,9] (in x_lds[1]), zero state
        {
            const int gb[3] = {0, 2, 3};    // gates i, g, o (f irrelevant: c0 = 0)
            bf16x8 bW[3][4];
            float  bb[3];
#pragma unroll
            for (int j = 0; j < 3; ++j) {
                int row = (gb[j] * 4 + w) * 16 + c;
#pragma unroll
                for (int kk = 0; kk < 4; ++kk)
                    bW[j][kk] = *(const bf16x8*)(ws + WS_WIH_B + row * FF + kk * 32 + koff);
                int u = gb[j] * 64 + w * 16 + c;
                bb[j] = bih_b[u] + bhh_b[u];
            }
            const char* xb = (const char*)x_lds[(KK - 1) & 1];
#pragma unroll
            for (int r = 0; r < 2; ++r) {
                f32x4 a0 = (f32x4){bb[0], bb[0], bb[0], bb[0]};
                f32x4 a1 = (f32x4){bb[1], bb[1], bb[1], bb[1]};
                f32x4 a2 = (f32x4){bb[2], bb[2], bb[2], bb[2]};
                const char* rp = xb + (r * 16 + c) * 256;
                bf16x8 xa[4];
#pragma unroll
                for (int kk = 0; kk < 4; ++kk)
                    xa[kk] = *(const bf16x8*)(rp + ((kk * 64 + q * 16) ^ sw));
#pragma unroll
                for (int kk = 0; kk < 4; ++kk) {
                    a0 = __builtin_amdgcn_mfma_f32_16x16x32_bf16(xa[kk], bW[0][kk], a0, 0, 0, 0);
                    a1 = __builtin_amdgcn_mfma_f32_16x16x32_bf16(xa[kk], bW[1][kk], a1, 0, 0, 0);
                    a2 = __builtin_amdgcn_mfma_f32_16x16x32_bf16(xa[kk], bW[2][kk], a2, 0, 0, 0);
                }
#pragma unroll
                for (int reg = 0; reg < 4; ++reg) {
                    float gi = fast_sig(a0[reg]);
                    float gg = fast_tanh(a1[reg]);
                    float go = fast_sig(a2[reg]);
                    float hb2 = go * fast_tanh(gi * gg);
                    int node = node_base + r * 16 + q * 4 + reg;
                    if (node < NN) out[(size_t)node * 128 + 64 + w * 16 + c] = hb2;
                }
            }
        }
    }
}

extern "C" void kernel_launch(void* const* d_in, const int* in_sizes, int n_in,
                              void* d_out, int out_size, void* d_ws, size_t ws_size,
                              hipStream_t stream) {
    const int*   nidx  = (const int*)d_in[0];
    const float* tab   = (const float*)d_in[1];
    const float* Wih_f = (const float*)d_in[2];
    const float* Whh_f = (const float*)d_in[3];
    const float* bih_f = (const float*)d_in[4];
    const float* bhh_f = (const float*)d_in[5];
    const float* Wih_b = (const float*)d_in[6];
    // d_in[7] = Whh_b: mathematically unused (h0 = 0 for the backward stream)
    const float* bih_b = (const float*)d_in[8];
    const float* bhh_b = (const float*)d_in[9];
    __bf16* ws  = (__bf16*)d_ws;      // 160 KB scratch
    float*  out = (float*)d_out;      // output is f32

    hipLaunchKernelGGL(cvt_weights_kernel, dim3(32768 / 256), dim3(256), 0, stream,
                       Wih_f, Whh_f, Wih_b, ws);

    hipLaunchKernelGGL(lstm_agg_kernel, dim3(GRID), dim3(256), 0, stream,
                       nidx, tab, bih_f, bhh_f, bih_b, bhh_b, ws, out);
}